// Round 1
// baseline (441.054 us; speedup 1.0000x reference)
//
#include <hip/hip_runtime.h>
#include <cstdint>
#include <cstddef>

#define IN_F 4096
#define OUT_F 11008
#define M_ROWS 4096
#define QZ_STRIDE (OUT_F / 8) /* 1376 */

typedef __attribute__((ext_vector_type(4))) float f32x4;
typedef __attribute__((ext_vector_type(8))) __bf16 bf16x8;
typedef uint32_t u32;
typedef uint16_t u16;

__device__ __forceinline__ u16 f2bf(float f) {
  u32 u = __builtin_bit_cast(u32, f);
  u += 0x7FFFu + ((u >> 16) & 1u);
  return (u16)(u >> 16);
}

// ---------------- x fp32 -> bf16 ----------------
__global__ void conv_x_kernel(const float* __restrict__ x, u16* __restrict__ xb) {
  const int total4 = (M_ROWS * IN_F) / 4;
  for (int i = blockIdx.x * blockDim.x + threadIdx.x; i < total4;
       i += gridDim.x * blockDim.x) {
    float4 v = reinterpret_cast<const float4*>(x)[i];
    uint2 o;
    o.x = (u32)f2bf(v.x) | ((u32)f2bf(v.y) << 16);
    o.y = (u32)f2bf(v.z) | ((u32)f2bf(v.w) << 16);
    reinterpret_cast<uint2*>(xb)[i] = o;
  }
}

// ------- dequant qweight -> WT [OUT_F][IN_F] bf16 (transposed, K contiguous) -------
__global__ void dequant_kernel(const int* __restrict__ qw, const int* __restrict__ qz,
                               const float* __restrict__ sc, u16* __restrict__ wt) {
  const int nl = threadIdx.x & 31, rl = threadIdx.x >> 5;
  const int n = blockIdx.x * 32 + nl;
  const int r = blockIdx.y * 8 + rl; // qweight row -> k = 8r..8r+7
  const int g = r >> 4;              // k/128
  u32 q = (u32)qw[(size_t)r * OUT_F + n];
  const int z = (int)(((u32)qz[g * QZ_STRIDE + (n >> 3)] >> (4 * (n & 7))) & 15u);
  const float s = sc[g * OUT_F + n];
  u32 o[4];
#pragma unroll
  for (int e = 0; e < 4; ++e) {
    u16 lo = f2bf(s * (float)((int)((q >> (8 * e)) & 15u) - z));
    u16 hi = f2bf(s * (float)((int)((q >> (8 * e + 4)) & 15u) - z));
    o[e] = (u32)lo | ((u32)hi << 16);
  }
  *reinterpret_cast<uint4*>(wt + (size_t)n * IN_F + r * 8) =
      make_uint4(o[0], o[1], o[2], o[3]);
}

// ---------------- GEMM: C[m][n] = sum_k A[m][k]*WT[n][k] + bias[n] ----------------
// 128x128 tile, BK=64, 4 waves (2x2), wave tile 64x64, mfma 16x16x32 bf16.
template <bool FUSED>
__global__ __launch_bounds__(256, 2) void gemm_kernel(
    const u16* __restrict__ xb, const u16* __restrict__ wt,
    const float* __restrict__ x, const int* __restrict__ qw,
    const int* __restrict__ qz, const float* __restrict__ sc,
    const float* __restrict__ bias, float* __restrict__ out) {
  __shared__ u16 As[128 * 64];
  __shared__ u16 Bs[128 * 64];
  const int tid = threadIdx.x;
  const int lane = tid & 63, wid = tid >> 6;
  const int bm = blockIdx.x & 31, bn = blockIdx.x >> 5;
  const int m0 = bm * 128, n0 = bn * 128;
  const int wr = wid >> 1, wc = wid & 1;
  const int frow = lane & 15, fk = (lane >> 4) * 8;
  f32x4 acc[4][4] = {};

  for (int kt = 0; kt < 64; ++kt) {
    const int k0 = kt * 64;
    if constexpr (FUSED) {
      // ---- A: x fp32 -> bf16 into LDS ----
#pragma unroll
      for (int it = 0; it < 8; ++it) {
        int c = it * 256 + tid;
        int row = c >> 4, c4 = c & 15;
        float4 v = *reinterpret_cast<const float4*>(
            x + (size_t)(m0 + row) * IN_F + k0 + c4 * 4);
        uint2 o;
        o.x = (u32)f2bf(v.x) | ((u32)f2bf(v.y) << 16);
        o.y = (u32)f2bf(v.z) | ((u32)f2bf(v.w) << 16);
        *reinterpret_cast<uint2*>(As + row * 64 + c4 * 4) = o;
      }
      // ---- B: fused dequant into LDS [n][k] ----
      {
        int nl = tid & 127, rq = tid >> 7;
        int n = n0 + nl;
        int g = k0 >> 7;
        int z = (int)(((u32)qz[g * QZ_STRIDE + (n >> 3)] >> (4 * (n & 7))) & 15u);
        float s = sc[g * OUT_F + n];
#pragma unroll
        for (int j = 0; j < 4; ++j) {
          int r = (k0 >> 3) + rq * 4 + j;
          u32 q = (u32)qw[(size_t)r * OUT_F + n];
          u32 o[4];
#pragma unroll
          for (int e = 0; e < 4; ++e) {
            u16 lo = f2bf(s * (float)((int)((q >> (8 * e)) & 15u) - z));
            u16 hi = f2bf(s * (float)((int)((q >> (8 * e + 4)) & 15u) - z));
            o[e] = (u32)lo | ((u32)hi << 16);
          }
          *reinterpret_cast<uint4*>(Bs + nl * 64 + (rq * 4 + j) * 8) =
              make_uint4(o[0], o[1], o[2], o[3]);
        }
      }
    } else {
      // ---- direct global->LDS staging, width 16, linear LDS ----
#pragma unroll
      for (int j = 0; j < 4; ++j) {
        int slot = wid * 4 + j; // 0..15, each = 1KB = 8 rows of 128B
        int row = slot * 8 + (lane >> 3);
        int ch = lane & 7;
        __builtin_amdgcn_global_load_lds(
            (__attribute__((address_space(1))) void*)(xb + (size_t)(m0 + row) * IN_F + k0 + ch * 8),
            (__attribute__((address_space(3))) void*)(As + slot * 512), 16, 0, 0);
        __builtin_amdgcn_global_load_lds(
            (__attribute__((address_space(1))) void*)(wt + (size_t)(n0 + row) * IN_F + k0 + ch * 8),
            (__attribute__((address_space(3))) void*)(Bs + slot * 512), 16, 0, 0);
      }
    }
    __syncthreads();

#pragma unroll
    for (int kk = 0; kk < 64; kk += 32) {
      bf16x8 a[4], b[4];
#pragma unroll
      for (int mi = 0; mi < 4; ++mi)
        a[mi] = *reinterpret_cast<const bf16x8*>(
            As + (wr * 64 + mi * 16 + frow) * 64 + kk + fk);
#pragma unroll
      for (int ni = 0; ni < 4; ++ni)
        b[ni] = *reinterpret_cast<const bf16x8*>(
            Bs + (wc * 64 + ni * 16 + frow) * 64 + kk + fk);
#pragma unroll
      for (int mi = 0; mi < 4; ++mi)
#pragma unroll
        for (int ni = 0; ni < 4; ++ni)
          acc[mi][ni] = __builtin_amdgcn_mfma_f32_16x16x32_bf16(
              a[mi], b[ni], acc[mi][ni], 0, 0, 0);
    }
    __syncthreads();
  }

  // epilogue: C/D layout col = lane&15, row = (lane>>4)*4 + reg
  const int crow = (lane >> 4) * 4, ccol = lane & 15;
#pragma unroll
  for (int mi = 0; mi < 4; ++mi) {
#pragma unroll
    for (int ni = 0; ni < 4; ++ni) {
      int col = n0 + wc * 64 + ni * 16 + ccol;
      float bv = bias[col];
      int rowb = m0 + wr * 64 + mi * 16 + crow;
#pragma unroll
      for (int r2 = 0; r2 < 4; ++r2)
        out[(size_t)(rowb + r2) * OUT_F + col] = acc[mi][ni][r2] + bv;
    }
  }
}

extern "C" void kernel_launch(void* const* d_in, const int* in_sizes, int n_in,
                              void* d_out, int out_size, void* d_ws, size_t ws_size,
                              hipStream_t stream) {
  const float* x = (const float*)d_in[0];
  const int* qw = (const int*)d_in[1];
  const float* sc = (const float*)d_in[2];
  const int* qz = (const int*)d_in[3];
  const float* bias = (const float*)d_in[4];
  float* out = (float*)d_out;

  const size_t xb_bytes = (size_t)M_ROWS * IN_F * 2;  // 32 MiB
  const size_t wt_bytes = (size_t)OUT_F * IN_F * 2;   // ~86 MiB
  dim3 gemm_grid(32 * 86);  // bm fastest (bid&31), bn = bid>>5

  if (ws_size >= xb_bytes + wt_bytes) {
    u16* xb = (u16*)d_ws;
    u16* wtp = (u16*)((char*)d_ws + xb_bytes);
    hipLaunchKernelGGL(conv_x_kernel, dim3(2048), dim3(256), 0, stream, x, xb);
    hipLaunchKernelGGL(dequant_kernel, dim3(OUT_F / 32, 512 / 8), dim3(256), 0,
                       stream, qw, qz, sc, wtp);
    hipLaunchKernelGGL((gemm_kernel<false>), gemm_grid, dim3(256), 0, stream,
                       xb, wtp, nullptr, nullptr, nullptr, nullptr, bias, out);
  } else {
    hipLaunchKernelGGL((gemm_kernel<true>), gemm_grid, dim3(256), 0, stream,
                       nullptr, nullptr, x, qw, qz, sc, bias, out);
  }
}